// Round 5
// baseline (348.219 us; speedup 1.0000x reference)
//
#include <hip/hip_runtime.h>

// COO SpMM: out[row[e], :] += values[e] * b[col[e], :]
// N=100000, E=1600000, D=128, fp32.
// v4: scatter processes 4 edges/thread (int4/float4 coalesced edge loads,
//     4 independent cursor atomics in flight) to attack atomic latency.
//     Gather unchanged from v3b (8-wide shfl-broadcast MLP).

#define D_DIM 128
#define OVF_MAX 65536

typedef float fx4 __attribute__((ext_vector_type(4)));  // native vec for NT store

// ---------------- scatter into padded row buckets, 4 edges/thread ----------------
__global__ void scatter_slots4_kernel(const int* __restrict__ rows,
                                      const int* __restrict__ cols,
                                      const float* __restrict__ vals,
                                      int* __restrict__ cursor,
                                      int2* __restrict__ slots,
                                      int* __restrict__ ovf_cnt,
                                      int* __restrict__ ovf_list,
                                      int E4, int E, int S) {
    int t = blockIdx.x * blockDim.x + threadIdx.x;
    if (t >= E4) return;
    int e0 = t * 4;

    int4   r4 = ((const int4*)rows)[t];
    int4   c4 = ((const int4*)cols)[t];
    float4 v4 = ((const float4*)vals)[t];

    int r[4] = {r4.x, r4.y, r4.z, r4.w};
    int c[4] = {c4.x, c4.y, c4.z, c4.w};
    float v[4] = {v4.x, v4.y, v4.z, v4.w};

    int pos[4];
#pragma unroll
    for (int j = 0; j < 4; ++j)
        pos[j] = atomicAdd(&cursor[r[j]], 1);   // 4 independent atomics in flight

#pragma unroll
    for (int j = 0; j < 4; ++j) {
        if (pos[j] < S) {
            slots[(size_t)r[j] * S + pos[j]] = make_int2(c[j], __float_as_int(v[j]));
        } else {
            int k = atomicAdd(ovf_cnt, 1);
            if (k < OVF_MAX) ovf_list[k] = e0 + j;
        }
    }
}

// tail: E % 4 edges
__global__ void scatter_tail_kernel(const int* __restrict__ rows,
                                    const int* __restrict__ cols,
                                    const float* __restrict__ vals,
                                    int* __restrict__ cursor,
                                    int2* __restrict__ slots,
                                    int* __restrict__ ovf_cnt,
                                    int* __restrict__ ovf_list,
                                    int start, int E, int S) {
    int e = start + blockIdx.x * blockDim.x + threadIdx.x;
    if (e >= E) return;
    int r = rows[e];
    int pos = atomicAdd(&cursor[r], 1);
    if (pos < S) {
        slots[(size_t)r * S + pos] = make_int2(cols[e], __float_as_int(vals[e]));
    } else {
        int k = atomicAdd(ovf_cnt, 1);
        if (k < OVF_MAX) ovf_list[k] = e;
    }
}

// ---------------- gather-accumulate with 8-wide MLP ----------------
// 32 lanes per row, each lane owns one float4 of the 128-wide row.
__global__ __launch_bounds__(256) void gather_slots_kernel(
        const int* __restrict__ cursor,
        const int2* __restrict__ slots,
        const float* __restrict__ b,
        float* __restrict__ out, int N, int S) {
    int t = blockIdx.x * blockDim.x + threadIdx.x;
    int r = t >> 5;
    if (r >= N) return;
    int lane = t & 31;

    int cnt = cursor[r];
    if (cnt > S) cnt = S;
    const int2* rs = slots + (size_t)r * S;

    float4 acc = make_float4(0.f, 0.f, 0.f, 0.f);
    for (int base = 0; base < cnt; base += 8) {
        int slot_idx = base + (lane & 7);
        int2 ev = rs[slot_idx];                 // in-bounds: base+7 <= S-1
        bool valid = slot_idx < cnt;
        int   c = valid ? ev.x : 0;             // invalid -> b[0], weight 0
        float v = valid ? __int_as_float(ev.y) : 0.0f;
#pragma unroll
        for (int i = 0; i < 8; ++i) {
            int   ci = __shfl(c, i, 8);
            float vi = __shfl(v, i, 8);
            float4 bv = ((const float4*)(b + (size_t)ci * D_DIM))[lane];
            acc.x += vi * bv.x;
            acc.y += vi * bv.y;
            acc.z += vi * bv.z;
            acc.w += vi * bv.w;
        }
    }
    fx4 accv = {acc.x, acc.y, acc.z, acc.w};
    __builtin_nontemporal_store(accv, (fx4*)(out + (size_t)r * D_DIM) + lane);
}

// ---------------- overflow fixup (normally 0 items) ----------------
__global__ void fixup_kernel(const int* __restrict__ ovf_cnt,
                             const int* __restrict__ ovf_list,
                             const int* __restrict__ rows,
                             const int* __restrict__ cols,
                             const float* __restrict__ vals,
                             const float* __restrict__ b,
                             float* __restrict__ out) {
    int items = *ovf_cnt;
    if (items > OVF_MAX) items = OVF_MAX;
    int gsz  = (gridDim.x * blockDim.x) >> 5;
    int gid  = (blockIdx.x * blockDim.x + threadIdx.x) >> 5;
    int lane = threadIdx.x & 31;
    for (int i = gid; i < items; i += gsz) {
        int e = ovf_list[i];
        int r = rows[e];
        int c = cols[e];
        float v = vals[e];
        float4 bv = ((const float4*)(b + (size_t)c * D_DIM))[lane];
        float* op = out + (size_t)r * D_DIM + (size_t)lane * 4;
        atomicAdd(op + 0, v * bv.x);
        atomicAdd(op + 1, v * bv.y);
        atomicAdd(op + 2, v * bv.z);
        atomicAdd(op + 3, v * bv.w);
    }
}

// ---------------- fallback (v1 atomic) ----------------
__global__ void spmm_atomic_kernel(const int* __restrict__ rows,
                                   const int* __restrict__ cols,
                                   const float* __restrict__ vals,
                                   const float* __restrict__ b,
                                   float* __restrict__ out, int E) {
    int t = blockIdx.x * blockDim.x + threadIdx.x;
    int e = t >> 5;
    if (e >= E) return;
    int lane = t & 31;
    int r = rows[e];
    int c = cols[e];
    float v = vals[e];
    float4 bv = ((const float4*)(b + (size_t)c * D_DIM))[lane];
    float* op = out + (size_t)r * D_DIM + (size_t)lane * 4;
    atomicAdd(op + 0, v * bv.x);
    atomicAdd(op + 1, v * bv.y);
    atomicAdd(op + 2, v * bv.z);
    atomicAdd(op + 3, v * bv.w);
}

extern "C" void kernel_launch(void* const* d_in, const int* in_sizes, int n_in,
                              void* d_out, int out_size, void* d_ws, size_t ws_size,
                              hipStream_t stream) {
    const int*   indices = (const int*)d_in[0];
    const float* vals    = (const float*)d_in[1];
    const float* b       = (const float*)d_in[3];
    float*       out     = (float*)d_out;

    int E = in_sizes[1];
    int N = out_size / D_DIM;
    const int* rows = indices;
    const int* cols = indices + E;

    // ---- workspace layout: cursor[N] | ovf_cnt | ovf_list[OVF_MAX] | slots[N*S]
    size_t fixed     = (size_t)N * 4 + 4 + (size_t)OVF_MAX * 4;
    size_t slots_off = (fixed + 255) & ~(size_t)255;

    int S = 0;
    if (ws_size >= slots_off + (size_t)N * 64 * 8)      S = 64;
    else if (ws_size >= slots_off + (size_t)N * 48 * 8) S = 48;
    else if (ws_size >= slots_off + (size_t)N * 32 * 8) S = 32;

    if (S == 0) {
        // fallback: atomic scatter (v1)
        (void)hipMemsetAsync(d_out, 0, (size_t)out_size * sizeof(float), stream);
        long long total = (long long)E * 32;
        int blocks = (int)((total + 255) / 256);
        spmm_atomic_kernel<<<blocks, 256, 0, stream>>>(rows, cols, vals, b, out, E);
        return;
    }

    char* w = (char*)d_ws;
    int*  cursor   = (int*)w;
    int*  ovf_cnt  = (int*)(w + (size_t)N * 4);
    int*  ovf_list = (int*)(w + (size_t)N * 4 + 4);
    int2* slots    = (int2*)(w + slots_off);

    // zero cursor + ovf_cnt in one memset (ws is re-poisoned each call)
    (void)hipMemsetAsync(cursor, 0, (size_t)N * 4 + 4, stream);

    // scatter: 4 edges per thread
    int E4 = E / 4;
    if (E4 > 0)
        scatter_slots4_kernel<<<(E4 + 255) / 256, 256, 0, stream>>>(
            rows, cols, vals, cursor, slots, ovf_cnt, ovf_list, E4, E, S);
    int tail_start = E4 * 4;
    int tail = E - tail_start;
    if (tail > 0)
        scatter_tail_kernel<<<1, 256, 0, stream>>>(
            rows, cols, vals, cursor, slots, ovf_cnt, ovf_list, tail_start, E, S);

    long long total = (long long)N * 32;
    int blocks = (int)((total + 255) / 256);
    gather_slots_kernel<<<blocks, 256, 0, stream>>>(cursor, slots, b, out, N, S);

    fixup_kernel<<<8, 256, 0, stream>>>(ovf_cnt, ovf_list, rows, cols, vals, b, out);
}